// Round 6
// baseline (93.769 us; speedup 1.0000x reference)
//
#include <hip/hip_runtime.h>
#include <hip/hip_bf16.h>

#define LOG2E 1.4426950408889634f

typedef __attribute__((ext_vector_type(8))) short bf16x8;
typedef __attribute__((ext_vector_type(4))) float f32x4;
typedef __attribute__((ext_vector_type(2))) float v2f;

static __device__ __forceinline__ float fast_exp2(float x) {
    return __builtin_amdgcn_exp2f(x);
}
static __device__ __forceinline__ short bf16bits(float f) {
    __hip_bfloat16 b = __float2bfloat16(f);   // RNE
    return *reinterpret_cast<short*>(&b);
}
// pack {lo -> bits[15:0], hi -> bits[31:16]} as 2x bf16 (no inline asm; compiler lowers)
static __device__ __forceinline__ unsigned packbf(float lo, float hi) {
    return (unsigned)(unsigned short)bf16bits(lo)
         | ((unsigned)(unsigned short)bf16bits(hi) << 16);
}

__global__ void wconv(const float* __restrict__ W, short* __restrict__ Wb) {
    const int i = blockIdx.x * 256 + threadIdx.x;   // 16384 elems
    Wb[i] = bf16bits(W[i]);
}

// One block per graph n = b*T + t.  A=50 nodes, D=128, H=32 heads, C=4.
// A: X = h @ W^T (MFMA 16x16x32 bf16), X stored transposed bf16 xsT[col][j]
//    (rows 50..63 true zeros), col 128 = ones.
// Then 2 phases of 16 heads:
//  B: tables {Es,Fs}={exp2(asc),exp2(.2*asc)}, {Ed,Fd} likewise (zeros for a>=50).
//  C: P generated in-register: p_ij = max(Ed_i*Es_j, Fd_i*Fs_j)
//     ( == exp2(leaky_relu(ad_i+as_j)), exp2 monotone + factorized ), diag zeroed
//     in-gen; MFMA P @ [X_h | 1]: cols 0..3 aggregate, col 4 = denominator l.
// LDS 34.96 KB -> 4 blocks/CU.
template<bool PRE>
__global__ __launch_bounds__(256, 4) void gat_fused(
    const float* __restrict__ hsrc,
    const float* __restrict__ W,
    const short* __restrict__ Wb,
    const float* __restrict__ att_src,
    const float* __restrict__ att_dst,
    const float* __restrict__ bias,
    float* __restrict__ out)
{
    constexpr int A = 50, T = 256, D = 128;
    constexpr int XJ = 72;                          // xsT j-stride (144B: 4-ish bank spread)
    __shared__ __align__(16) char smem[16384 + 129 * XJ * 2];   // 34960 B
    float* esfs = (float*)smem;                     // [16][64] {Es,Fs}  (8 KB)
    float* edfd = (float*)(smem + 8192);            // [16][64] {Ed,Fd}  (8 KB)
    short* xsT  = (short*)(smem + 16384);           // [129][72] bf16 X^T, col 128 = ones
    short* hsb  = (short*)smem;                     // overlay: [64][128] bf16 swizzled (phase A)

    const int n = blockIdx.x;
    const int b = n >> 8;                           // T = 256
    const int t = n & 255;
    const int tid = threadIdx.x;
    const int lane = tid & 63, lr = lane & 15, lg = lane >> 4;
    const int w = tid >> 6;

    // ---- A1: stage h[b,:,t,:] -> hsb bf16 swizzled (rows 50..63 zero); ones col ----
    const float4* hg4 = (const float4*)hsrc;
    for (int idx = tid; idx < 64 * 32; idx += 256) {
        const int a = idx >> 5, k4 = idx & 31;
        short4 pk = {0, 0, 0, 0};
        if (a < A) {
            const float4 hv = hg4[((size_t)(b * A + a) * T + t) * 32 + k4];
            pk.x = bf16bits(hv.x); pk.y = bf16bits(hv.y);
            pk.z = bf16bits(hv.z); pk.w = bf16bits(hv.w);
        }
        const int swz = (k4 >> 1) ^ (a & 7);        // 16B-chunk swizzle
        *(short4*)&hsb[a * 128 + swz * 8 + (k4 & 1) * 4] = pk;
    }
    if (tid < 64) xsT[128 * XJ + tid] = (short)0x3F80;   // bf16 1.0, rows 0..63
    __syncthreads();

    // ---- A2: X = h @ W^T (MFMA); write xsT[col][row] bf16, rows 0..63 ----
    {
        const int n0 = w * 32;
        f32x4 acc[4][2];
        #pragma unroll
        for (int m = 0; m < 4; ++m) {
            acc[m][0] = (f32x4){0.f, 0.f, 0.f, 0.f};
            acc[m][1] = (f32x4){0.f, 0.f, 0.f, 0.f};
        }
        #pragma unroll
        for (int kk = 0; kk < 4; ++kk) {
            bf16x8 bf0, bf1;
            if (PRE) {
                const bf16x8* Wb8 = (const bf16x8*)Wb;
                bf0 = Wb8[(size_t)(n0 + lr) * 16 + kk * 4 + lg];
                bf1 = Wb8[(size_t)(n0 + 16 + lr) * 16 + kk * 4 + lg];
            } else {
                const float4* W4 = (const float4*)W;
                const int kb = kk * 8 + lg * 2;
                const float4 wa = W4[(size_t)(n0 + lr) * 32 + kb];
                const float4 wb = W4[(size_t)(n0 + lr) * 32 + kb + 1];
                const float4 wc = W4[(size_t)(n0 + 16 + lr) * 32 + kb];
                const float4 wd = W4[(size_t)(n0 + 16 + lr) * 32 + kb + 1];
                bf0[0] = bf16bits(wa.x); bf0[1] = bf16bits(wa.y);
                bf0[2] = bf16bits(wa.z); bf0[3] = bf16bits(wa.w);
                bf0[4] = bf16bits(wb.x); bf0[5] = bf16bits(wb.y);
                bf0[6] = bf16bits(wb.z); bf0[7] = bf16bits(wb.w);
                bf1[0] = bf16bits(wc.x); bf1[1] = bf16bits(wc.y);
                bf1[2] = bf16bits(wc.z); bf1[3] = bf16bits(wc.w);
                bf1[4] = bf16bits(wd.x); bf1[5] = bf16bits(wd.y);
                bf1[6] = bf16bits(wd.z); bf1[7] = bf16bits(wd.w);
            }
            #pragma unroll
            for (int m = 0; m < 4; ++m) {
                const int row = m * 16 + lr;
                const int chunk = (kk * 4 + lg) ^ (row & 7);
                const bf16x8 af = *(const bf16x8*)&hsb[row * 128 + chunk * 8];
                acc[m][0] = __builtin_amdgcn_mfma_f32_16x16x32_bf16(af, bf0, acc[m][0], 0, 0, 0);
                acc[m][1] = __builtin_amdgcn_mfma_f32_16x16x32_bf16(af, bf1, acc[m][1], 0, 0, 0);
            }
        }
        // D layout: row = m*16 + lg*4 + r, col = n0 + nt*16 + lr  -> xsT[col][row]
        #pragma unroll
        for (int m = 0; m < 4; ++m) {
            const int row0 = m * 16 + lg * 4;       // 0..60, all written (rows>=50 are 0)
            #pragma unroll
            for (int nt = 0; nt < 2; ++nt) {
                const int col = n0 + nt * 16 + lr;
                const unsigned w0 = packbf(acc[m][nt][0], acc[m][nt][1]);
                const unsigned w1 = packbf(acc[m][nt][2], acc[m][nt][3]);
                *(uint2*)&xsT[col * XJ + row0] = (uint2){w0, w1};
            }
        }
    }
    __syncthreads();

    const float4* as4 = (const float4*)att_src;
    const float4* ad4 = (const float4*)att_dst;

    #pragma unroll 1
    for (int ph = 0; ph < 2; ++ph) {
        // ---- B: tables for heads ph*16 .. ph*16+15 (a>=50 -> zeros) ----
        #pragma unroll
        for (int p = 0; p < 4; ++p) {
            const int idx = p * 256 + tid;           // = hl*64 + a
            const int hl = idx >> 6, a = idx & 63;
            v2f sf = (v2f){0.f, 0.f}, df = (v2f){0.f, 0.f};
            if (a < A) {
                const int hg = ph * 16 + hl;
                const int cb = (hg * 4) * XJ + a;
                const float x0 = __uint_as_float((unsigned)(unsigned short)xsT[cb] << 16);
                const float x1 = __uint_as_float((unsigned)(unsigned short)xsT[cb + XJ] << 16);
                const float x2 = __uint_as_float((unsigned)(unsigned short)xsT[cb + 2 * XJ] << 16);
                const float x3 = __uint_as_float((unsigned)(unsigned short)xsT[cb + 3 * XJ] << 16);
                const float4 s4 = as4[hg], d4 = ad4[hg];
                const float as = LOG2E * fmaf(x3, s4.w, fmaf(x2, s4.z, fmaf(x1, s4.y, x0 * s4.x)));
                const float ad = LOG2E * fmaf(x3, d4.w, fmaf(x2, d4.z, fmaf(x1, d4.y, x0 * d4.x)));
                sf = (v2f){fast_exp2(as), fast_exp2(0.2f * as)};
                df = (v2f){fast_exp2(ad), fast_exp2(0.2f * ad)};
            }
            *(v2f*)&esfs[idx * 2] = sf;
            *(v2f*)&edfd[idx * 2] = df;
        }
        __syncthreads();

        // ---- C: wave handles 4 heads; P in-register -> MFMA P @ [X_h | 1] ----
        #pragma unroll 1
        for (int u = 0; u < 4; ++u) {
            const int hl = w * 4 + u;
            const int hg = ph * 16 + hl;
            const int colmap = (lr < 4) ? (hg * 4 + lr) : 128;   // data cols, then ones
            f32x4 acc[4];
            #pragma unroll
            for (int m = 0; m < 4; ++m) acc[m] = (f32x4){0.f, 0.f, 0.f, 0.f};
            #pragma unroll
            for (int kt = 0; kt < 2; ++kt) {
                const int k0 = kt * 32;
                const int j0 = k0 + lg * 8;          // lane's 8 source nodes (<= 63)
                const float4* ep = (const float4*)&esfs[(hl * 64 + j0) * 2];
                const float4 e0 = ep[0], e1 = ep[1], e2 = ep[2], e3 = ep[3];
                union { uint4 q; bf16x8 v; } bfr;
                bfr.q = *(const uint4*)&xsT[colmap * XJ + j0];
                #pragma unroll
                for (int m = 0; m < 4; ++m) {
                    const int row = m * 16 + lr;
                    const v2f dd = *(const v2f*)&edfd[(hl * 64 + row) * 2];
                    float p0 = fmaxf(dd.x * e0.x, dd.y * e0.y);
                    float p1 = fmaxf(dd.x * e0.z, dd.y * e0.w);
                    float p2 = fmaxf(dd.x * e1.x, dd.y * e1.y);
                    float p3 = fmaxf(dd.x * e1.z, dd.y * e1.w);
                    float p4 = fmaxf(dd.x * e2.x, dd.y * e2.y);
                    float p5 = fmaxf(dd.x * e2.z, dd.y * e2.w);
                    float p6 = fmaxf(dd.x * e3.x, dd.y * e3.y);
                    float p7 = fmaxf(dd.x * e3.z, dd.y * e3.w);
                    const int dm = m * 16 - k0;
                    if (dm >= -15 && dm <= 23) {     // diag-crossing frags (folds at compile time)
                        const int dq = row - j0;
                        p0 = (dq == 0) ? 0.f : p0;
                        p1 = (dq == 1) ? 0.f : p1;
                        p2 = (dq == 2) ? 0.f : p2;
                        p3 = (dq == 3) ? 0.f : p3;
                        p4 = (dq == 4) ? 0.f : p4;
                        p5 = (dq == 5) ? 0.f : p5;
                        p6 = (dq == 6) ? 0.f : p6;
                        p7 = (dq == 7) ? 0.f : p7;
                    }
                    union { unsigned uu[4]; bf16x8 v; } afr;
                    afr.uu[0] = packbf(p0, p1);
                    afr.uu[1] = packbf(p2, p3);
                    afr.uu[2] = packbf(p4, p5);
                    afr.uu[3] = packbf(p6, p7);
                    acc[m] = __builtin_amdgcn_mfma_f32_16x16x32_bf16(afr.v, bfr.v, acc[m], 0, 0, 0);
                }
            }
            // epilogue: col 4 holds l = sum_j p; normalize cols 0..3, bias, store
            const float bv = bias[hg * 4 + (lr & 3)];
            #pragma unroll
            for (int m = 0; m < 4; ++m) {
                #pragma unroll
                for (int r = 0; r < 4; ++r) {
                    const float lsum = __shfl(acc[m][r], (lane & 48) | 4, 64);  // lane lr==4, same lg
                    const int row = m * 16 + lg * 4 + r;
                    if (lr < 4 && row < A) {
                        const float linv = __builtin_amdgcn_rcpf(fmaxf(lsum, 1e-20f));
                        const float o = fmaf(acc[m][r], linv, bv);
                        out[((size_t)(b * A + row) * T + t) * D + hg * 4 + lr] = o;
                    }
                }
            }
        }
        __syncthreads();
    }
}

extern "C" void kernel_launch(void* const* d_in, const int* in_sizes, int n_in,
                              void* d_out, int out_size, void* d_ws, size_t ws_size,
                              hipStream_t stream) {
    const float* h       = (const float*)d_in[0];
    const float* W       = (const float*)d_in[1];
    const float* att_src = (const float*)d_in[2];
    const float* att_dst = (const float*)d_in[3];
    const float* bias    = (const float*)d_in[4];
    float* out = (float*)d_out;
    dim3 grid(8 * 256);   // B*T graphs
    dim3 block(256);
    if (ws_size >= 128 * 128 * sizeof(short)) {
        short* Wb = (short*)d_ws;
        hipLaunchKernelGGL(wconv, dim3(64), block, 0, stream, W, Wb);
        hipLaunchKernelGGL(gat_fused<true>, grid, block, 0, stream,
                           h, W, Wb, att_src, att_dst, bias, out);
    } else {
        hipLaunchKernelGGL(gat_fused<false>, grid, block, 0, stream,
                           h, W, (const short*)nullptr, att_src, att_dst, bias, out);
    }
}

// Round 7
// 59.985 us; speedup vs baseline: 1.5632x; 1.5632x over previous
//
#include <hip/hip_runtime.h>
#include <hip/hip_bf16.h>

#define LOG2E 1.4426950408889634f

typedef __attribute__((ext_vector_type(8))) short bf16x8;
typedef __attribute__((ext_vector_type(4))) float f32x4;
typedef __attribute__((ext_vector_type(2))) float v2f;

static __device__ __forceinline__ float fast_exp2(float x) {
    return __builtin_amdgcn_exp2f(x);
}
static __device__ __forceinline__ short bf16bits(float f) {
    __hip_bfloat16 b = __float2bfloat16(f);   // RNE
    return *reinterpret_cast<short*>(&b);
}

__global__ void wconv(const float* __restrict__ W, short* __restrict__ Wb) {
    const int i = blockIdx.x * 256 + threadIdx.x;   // 16384 elems
    Wb[i] = bf16bits(W[i]);
}

// One block per graph n = b*T + t.  A=50 nodes, D=128, H=32 heads, C=4.
// Round-3 structure (proven 57.8us), one change: X stored bf16 (12.8 KB vs
// 26.4 KB f32) -> LDS 38.4 KB -> 4 blocks/CU (occupancy 25->33%).
// Phase A: X = h @ W^T via bf16 MFMA 16x16x32 (h staged in LDS bf16, swizzled).
// Phase B: factorized tables {Es,Fs},{Ed,Fd} = exp2({1,0.2}*logit-halves).
// Phase C: p = max(Ed*Es, Fd*Fs) [== exp2(leaky_relu(ad+as))], pk-fma
// aggregation over 7 destinations/lane, exact self-edge cancellation.
template<bool PRE>
__global__ __launch_bounds__(256, 4) void gat_fused(
    const float* __restrict__ hsrc,
    const float* __restrict__ W,
    const short* __restrict__ Wb,
    const float* __restrict__ att_src,
    const float* __restrict__ att_dst,
    const float* __restrict__ bias,
    float* __restrict__ out)
{
    constexpr int A = 50, T = 256, D = 128, H = 32;
    __shared__ __align__(16) char smem[25600 + 12800];   // 38400 B
    v2f*   EsFs = (v2f*)smem;                      // [A*H] {exp2(asc), exp2(.2*asc)}
    v2f*   EdFd = (v2f*)(smem + 12800);            // [A*H] {exp2(ads), exp2(.2*ads)}
    short* hsb  = (short*)smem;                    // overlay: bf16 h tile [64][128] (phase A)
    short* xsb  = (short*)(smem + 25600);          // bf16 X [50][128]

    const int n = blockIdx.x;
    const int b = n >> 8;                          // T = 256
    const int t = n & 255;
    const int tid = threadIdx.x;

    // ---- Phase A1: stage h[b,:,t,:] -> LDS bf16, zero-pad rows 50..63, swizzled ----
    const float4* hg4 = (const float4*)hsrc;
    for (int idx = tid; idx < 64 * 32; idx += 256) {
        const int a = idx >> 5, k4 = idx & 31;
        short4 pk = {0, 0, 0, 0};
        if (a < A) {
            const float4 hv = hg4[((size_t)(b * A + a) * T + t) * 32 + k4];
            pk.x = bf16bits(hv.x); pk.y = bf16bits(hv.y);
            pk.z = bf16bits(hv.z); pk.w = bf16bits(hv.w);
        }
        const int swz = (k4 >> 1) ^ (a & 7);       // 16B-chunk swizzle
        *(short4*)&hsb[a * 128 + swz * 8 + (k4 & 1) * 4] = pk;
    }
    __syncthreads();

    // ---- Phase A2: X[a][e] = sum_k h[a][k] W[e][k]  (MFMA 16x16x32 bf16) ----
    {
        const int wv = tid >> 6;
        const int lane = tid & 63;
        const int lr = lane & 15, lg = lane >> 4;
        const int n0 = wv * 32;
        f32x4 acc[4][2];
        #pragma unroll
        for (int m = 0; m < 4; ++m) {
            acc[m][0] = (f32x4){0.f, 0.f, 0.f, 0.f};
            acc[m][1] = (f32x4){0.f, 0.f, 0.f, 0.f};
        }
        #pragma unroll
        for (int kk = 0; kk < 4; ++kk) {
            bf16x8 bf0, bf1;
            if (PRE) {
                const bf16x8* Wb8 = (const bf16x8*)Wb;
                bf0 = Wb8[(size_t)(n0 + lr) * 16 + kk * 4 + lg];
                bf1 = Wb8[(size_t)(n0 + 16 + lr) * 16 + kk * 4 + lg];
            } else {
                const float4* W4 = (const float4*)W;
                const int kb = kk * 8 + lg * 2;
                const float4 wa = W4[(size_t)(n0 + lr) * 32 + kb];
                const float4 wb = W4[(size_t)(n0 + lr) * 32 + kb + 1];
                const float4 wc = W4[(size_t)(n0 + 16 + lr) * 32 + kb];
                const float4 wd = W4[(size_t)(n0 + 16 + lr) * 32 + kb + 1];
                bf0[0] = bf16bits(wa.x); bf0[1] = bf16bits(wa.y);
                bf0[2] = bf16bits(wa.z); bf0[3] = bf16bits(wa.w);
                bf0[4] = bf16bits(wb.x); bf0[5] = bf16bits(wb.y);
                bf0[6] = bf16bits(wb.z); bf0[7] = bf16bits(wb.w);
                bf1[0] = bf16bits(wc.x); bf1[1] = bf16bits(wc.y);
                bf1[2] = bf16bits(wc.z); bf1[3] = bf16bits(wc.w);
                bf1[4] = bf16bits(wd.x); bf1[5] = bf16bits(wd.y);
                bf1[6] = bf16bits(wd.z); bf1[7] = bf16bits(wd.w);
            }
            #pragma unroll
            for (int m = 0; m < 4; ++m) {
                const int row = m * 16 + lr;
                const int chunk = (kk * 4 + lg) ^ (row & 7);
                const bf16x8 af = *(const bf16x8*)&hsb[row * 128 + chunk * 8];
                acc[m][0] = __builtin_amdgcn_mfma_f32_16x16x32_bf16(af, bf0, acc[m][0], 0, 0, 0);
                acc[m][1] = __builtin_amdgcn_mfma_f32_16x16x32_bf16(af, bf1, acc[m][1], 0, 0, 0);
            }
        }
        // D layout: row = m*16 + lg*4 + r, col = n0 + nt*16 + lr  -> xsb[row][col] bf16
        #pragma unroll
        for (int m = 0; m < 4; ++m) {
            const int rb = m * 16 + lg * 4;
            #pragma unroll
            for (int nt = 0; nt < 2; ++nt) {
                const int col = n0 + nt * 16 + lr;
                #pragma unroll
                for (int r = 0; r < 4; ++r) {
                    if (rb + r < A) xsb[(rb + r) * D + col] = bf16bits(acc[m][nt][r]);
                }
            }
        }
    }
    __syncthreads();

    // ---- Phase B: factorized exp tables per (node, head) ----
    for (int idx = tid; idx < A * H; idx += 256) {
        const int hh = idx & 31, a = idx >> 5;
        const uint2 xq = *(const uint2*)&xsb[a * D + hh * 4];
        const float x0 = __uint_as_float(xq.x << 16);
        const float x1 = __uint_as_float(xq.x & 0xffff0000u);
        const float x2 = __uint_as_float(xq.y << 16);
        const float x3 = __uint_as_float(xq.y & 0xffff0000u);
        const float4 s4 = ((const float4*)att_src)[hh];
        const float4 d4 = ((const float4*)att_dst)[hh];
        const float asc = LOG2E * fmaf(x3, s4.w, fmaf(x2, s4.z, fmaf(x1, s4.y, x0 * s4.x)));
        const float ads = LOG2E * fmaf(x3, d4.w, fmaf(x2, d4.z, fmaf(x1, d4.y, x0 * d4.x)));
        EsFs[idx] = (v2f){fast_exp2(asc), fast_exp2(0.2f * asc)};
        EdFd[idx] = (v2f){fast_exp2(ads), fast_exp2(0.2f * ads)};
    }
    __syncthreads();

    // ---- Phase C: softmax + aggregation, register-blocked over destinations ----
    // lane owns head hh and 7 destinations i = ib + 8*r.
    {
        const int hh = tid & 31;
        const int ib = tid >> 5;                    // 0..7
        v2f acc01[7], acc23[7], df[7];
        float l[7];
        #pragma unroll
        for (int r = 0; r < 7; ++r) {
            const int i = ib + 8 * r;
            const int ii = (i < A) ? i : (A - 1);
            df[r] = EdFd[ii * H + hh];
            acc01[r] = (v2f){0.f, 0.f};
            acc23[r] = (v2f){0.f, 0.f};
            l[r] = 0.f;
        }
        #pragma unroll 5
        for (int j = 0; j < A; ++j) {
            const v2f sf = EsFs[j * H + hh];                     // b64 (broadcast pair)
            const uint2 xq = *(const uint2*)&xsb[j * D + hh * 4];
            const v2f x01 = (v2f){__uint_as_float(xq.x << 16),
                                  __uint_as_float(xq.x & 0xffff0000u)};
            const v2f x23 = (v2f){__uint_as_float(xq.y << 16),
                                  __uint_as_float(xq.y & 0xffff0000u)};
            #pragma unroll
            for (int r = 0; r < 7; ++r) {
                const v2f pe = df[r] * sf;                       // v_pk_mul_f32
                const float p = fmaxf(pe.x, pe.y);               // leaky+exp, 1 op
                l[r] += p;
                const v2f pp = (v2f){p, p};
                acc01[r] = __builtin_elementwise_fma(pp, x01, acc01[r]);  // v_pk_fma_f32
                acc23[r] = __builtin_elementwise_fma(pp, x23, acc23[r]);
            }
        }
        const float4 bv = ((const float4*)bias)[hh];
        #pragma unroll
        for (int r = 0; r < 7; ++r) {
            const int i = ib + 8 * r;
            if (i < A) {
                // remove self-edge (identical expression -> exact cancellation)
                const v2f sf = EsFs[i * H + hh];
                const uint2 xq = *(const uint2*)&xsb[i * D + hh * 4];
                const float xx0 = __uint_as_float(xq.x << 16);
                const float xx1 = __uint_as_float(xq.x & 0xffff0000u);
                const float xx2 = __uint_as_float(xq.y << 16);
                const float xx3 = __uint_as_float(xq.y & 0xffff0000u);
                const v2f pe = df[r] * sf;
                const float p = fmaxf(pe.x, pe.y);
                const float linv = 1.0f / (l[r] - p);
                float4 o;
                o.x = fmaf(acc01[r].x - p * xx0, linv, bv.x);
                o.y = fmaf(acc01[r].y - p * xx1, linv, bv.y);
                o.z = fmaf(acc23[r].x - p * xx2, linv, bv.z);
                o.w = fmaf(acc23[r].y - p * xx3, linv, bv.w);
                *(float4*)&out[((size_t)(b * A + i) * T + t) * D + hh * 4] = o;
            }
        }
    }
}

extern "C" void kernel_launch(void* const* d_in, const int* in_sizes, int n_in,
                              void* d_out, int out_size, void* d_ws, size_t ws_size,
                              hipStream_t stream) {
    const float* h       = (const float*)d_in[0];
    const float* W       = (const float*)d_in[1];
    const float* att_src = (const float*)d_in[2];
    const float* att_dst = (const float*)d_in[3];
    const float* bias    = (const float*)d_in[4];
    float* out = (float*)d_out;
    dim3 grid(8 * 256);   // B*T graphs
    dim3 block(256);
    if (ws_size >= 128 * 128 * sizeof(short)) {
        short* Wb = (short*)d_ws;
        hipLaunchKernelGGL(wconv, dim3(64), block, 0, stream, W, Wb);
        hipLaunchKernelGGL(gat_fused<true>, grid, block, 0, stream,
                           h, W, Wb, att_src, att_dst, bias, out);
    } else {
        hipLaunchKernelGGL(gat_fused<false>, grid, block, 0, stream,
                           h, W, (const short*)nullptr, att_src, att_dst, bias, out);
    }
}